// Round 15
// baseline (2729.465 us; speedup 1.0000x reference)
//
#include <hip/hip_runtime.h>

#define TB 256

typedef __attribute__((ext_vector_type(8))) short short8;
typedef __attribute__((ext_vector_type(4))) float f32x4;
typedef unsigned short u16;

constexpr int B_  = 2048;
constexpr int DIN = 1024;
constexpr int E   = 1024;
constexpr int F   = 16384;
constexpr int E3  = 3072;
constexpr int CH  = 4096;  // tier-B chunk

struct Ptr8 { void* p[8]; };

__device__ __forceinline__ u16 f2bf(float f) {
  union { float f; unsigned u; } v; v.f = f;
  unsigned r = v.u + 0x7fffu + ((v.u >> 16) & 1u);
  return (u16)(r >> 16);
}
__device__ __forceinline__ float bf2f(u16 u) {
  union { unsigned u; float f; } v; v.u = ((unsigned)u) << 16;
  return v.f;
}

__device__ __forceinline__ void gload16(const void* g, void* l) {
  __builtin_amdgcn_global_load_lds(
      (const __attribute__((address_space(1))) void*)g,
      (__attribute__((address_space(3))) void*)l, 16, 0, 0);
}

// XCD-aware tile swizzle (bijective when nwg % 8 == 0; else identity)
__device__ __forceinline__ void tile_xy(int& tx, int& ty) {
  int gx = gridDim.x;
  int nwg = gx * gridDim.y;
  int wg = blockIdx.y * gx + blockIdx.x;
  if ((nwg & 7) == 0) wg = (wg & 7) * (nwg >> 3) + (wg >> 3);
  tx = wg % gx; ty = wg / gx;
}

// LDS byte-offset swizzle: XOR 16B-granule index with (128B-line index & 7)
__device__ __forceinline__ int swz16(int o) {
  return o ^ (((o >> 7) & 7) << 4);
}

__global__ __launch_bounds__(256) void cvt_kernel(const float* __restrict__ s,
                                                  u16* __restrict__ d, int n) {
  int i = (blockIdx.x * 256 + threadIdx.x) * 4;
  if (i >= n) return;
  float4 v = *(const float4*)&s[i];
  ushort4 o;
  o.x = f2bf(v.x); o.y = f2bf(v.y); o.z = f2bf(v.z); o.w = f2bf(v.w);
  *(ushort4*)&d[i] = o;
}

__global__ __launch_bounds__(256) void fill_kernel(float* p, int n, float v) {
  int i = blockIdx.x * 256 + threadIdx.x;
  if (i < n) p[i] = v;
}

// out_bf16 = relu(sum_{j<ny} Y[j] + bias[col])
__global__ __launch_bounds__(256) void relu_multi_kernel(
    Ptr8 ys, int ny, const float* __restrict__ bias, u16* __restrict__ out) {
  size_t i = ((size_t)blockIdx.x * 256 + threadIdx.x) * 4;
  int col = (int)(i & 1023);
  float4 b = *(const float4*)&bias[col];
  float a0 = b.x, a1 = b.y, a2 = b.z, a3 = b.w;
  for (int j = 0; j < ny; ++j) {
    float4 z = *(const float4*)&((const float*)ys.p[j])[i];
    a0 += z.x; a1 += z.y; a2 += z.z; a3 += z.w;
  }
  ushort4 o;
  o.x = f2bf(a0 > 0.f ? a0 : 0.f);
  o.y = f2bf(a1 > 0.f ? a1 : 0.f);
  o.z = f2bf(a2 > 0.f ? a2 : 0.f);
  o.w = f2bf(a3 > 0.f ? a3 : 0.f);
  *(ushort4*)&out[i] = o;
}

// out_f32 = sum_{j<ny} Y[j] + bias[col]   (final Wout combine)
__global__ __launch_bounds__(256) void combine_out_kernel(
    Ptr8 ys, int ny, const float* __restrict__ bias, float* __restrict__ out) {
  size_t i = ((size_t)blockIdx.x * 256 + threadIdx.x) * 4;
  int col = (int)(i & 1023);
  float4 b = *(const float4*)&bias[col];
  float a0 = b.x, a1 = b.y, a2 = b.z, a3 = b.w;
  for (int j = 0; j < ny; ++j) {
    float4 z = *(const float4*)&((const float*)ys.p[j])[i];
    a0 += z.x; a1 += z.y; a2 += z.z; a3 += z.w;
  }
  out[i] = a0; out[i + 1] = a1; out[i + 2] = a2; out[i + 3] = a3;
}

// ======= 256x256 bf16 GEMM, BK=32, 2-slot dbuf, 64 KiB LDS (2 blocks/CU) ====
// Same verified r11 sync ledger (stage next -> reads -> MFMA -> vmcnt(0) ->
// barrier) and r12's verified row-pair-packed 16KB tile layout. Halving LDS
// doubles blocks/CU so a co-resident block fills barrier/drain shadows.
// EPI: 0 f32 plain store to pouts.p[blockIdx.z] (split-K), 1 bf16+bias,
//      4 gated bf16 in-place (gate may alias Out). EPI 1/4 coalesced store.
template <int EPI>
__global__ __launch_bounds__(512, 4) void gemm256(
    const u16* __restrict__ A, int sA,
    const u16* __restrict__ Bw, int sB,
    const float* __restrict__ bias, const u16* __restrict__ gate,
    void* __restrict__ Out, Ptr8 pouts, int ldOut, int ksz) {
  __shared__ __align__(16) char smem[65536];
  const int tid = threadIdx.x, lane = tid & 63, w = tid >> 6;
  const int wm = w >> 2, wn = w & 3;
  int tx, ty; tile_xy(tx, ty);
  const int m0 = tx * 256, n0 = ty * 256;
  const int k0 = blockIdx.z * ksz;
  const int nt = ksz >> 5;  // BK = 32
  const int lr = lane & 15;

  f32x4 acc[8][4] = {};

  // 16KB tile slot: 128B line = row-pair; L = pr*128 + sub*64 + kb
  // (row = 2*pr+sub, k-byte kb 0..63). Linear LDS dest, inverse-swizzled
  // global source (rule #21). Verified in r12.
  auto stage = [&](const u16* __restrict__ G, int gs, int gr0, int kk, int tb, int j) {
    int P = j * 8192 + w * 1024 + lane * 16;
    int L = swz16(P);
    int pr = L >> 7, sub = (L >> 6) & 1, kb = L & 63;
    gload16(G + (size_t)(gr0 + pr * 2 + sub) * gs + kk + (kb >> 1),
            &smem[tb + P]);
  };
  auto rdA = [&](int tb, int mf) -> short8 {
    int r = wm * 128 + mf * 16 + lr;
    int o = (r >> 1) * 128 + (r & 1) * 64 + (lane >> 4) * 16;
    return *(const short8*)&smem[tb + swz16(o)];
  };
  auto rdB = [&](int tb, int nf) -> short8 {
    int r = wn * 64 + nf * 16 + lr;
    int o = (r >> 1) * 128 + (r & 1) * 64 + (lane >> 4) * 16;
    return *(const short8*)&smem[tb + swz16(o)];
  };

  // prologue: tile 0 -> slot 0; publish.
#pragma unroll
  for (int j = 0; j < 2; ++j) stage(A, sA, m0, k0, 0, j);
#pragma unroll
  for (int j = 0; j < 2; ++j) stage(Bw, sB, n0, k0, 32768, j);
  asm volatile("s_waitcnt vmcnt(0)" ::: "memory");
  __builtin_amdgcn_sched_barrier(0);
  __builtin_amdgcn_s_barrier();

  int cur = 0;
  for (int t = 0; t < nt; ++t) {
    const int sa = cur * 16384;
    const int sb = 32768 + cur * 16384;
    if (t + 1 < nt) {
      const int sa2 = (cur ^ 1) * 16384;
      const int sb2 = 32768 + (cur ^ 1) * 16384;
#pragma unroll
      for (int j = 0; j < 2; ++j) stage(A, sA, m0, k0 + (t + 1) * 32, sa2, j);
#pragma unroll
      for (int j = 0; j < 2; ++j) stage(Bw, sB, n0, k0 + (t + 1) * 32, sb2, j);
    }
    short8 afr[8], bfr[4];
#pragma unroll
    for (int nf = 0; nf < 4; ++nf) bfr[nf] = rdB(sb, nf);
#pragma unroll
    for (int mf = 0; mf < 8; ++mf) afr[mf] = rdA(sa, mf);
    __builtin_amdgcn_s_setprio(1);
#pragma unroll
    for (int mf = 0; mf < 8; ++mf)
#pragma unroll
      for (int nf = 0; nf < 4; ++nf)
        acc[mf][nf] = __builtin_amdgcn_mfma_f32_16x16x32_bf16(
            afr[mf], bfr[nf], acc[mf][nf], 0, 0, 0);
    __builtin_amdgcn_s_setprio(0);
    if (t + 1 < nt) {
      asm volatile("s_waitcnt vmcnt(0)" ::: "memory");
      __builtin_amdgcn_sched_barrier(0);
      __builtin_amdgcn_s_barrier();
    }
    cur ^= 1;
  }

  if (EPI == 0) {
    float* Pf = (float*)pouts.p[blockIdx.z];
    const int rb = (lane >> 4) * 4;
#pragma unroll
    for (int mf = 0; mf < 8; ++mf) {
#pragma unroll
      for (int nf = 0; nf < 4; ++nf) {
        int row0 = m0 + wm * 128 + mf * 16 + rb;
        int col  = n0 + wn * 64 + nf * 16 + lr;
#pragma unroll
        for (int r = 0; r < 4; ++r)
          Pf[(size_t)(row0 + r) * ldOut + col] = acc[mf][nf][r];
      }
    }
  } else {
    // LDS-staged coalesced bf16 store: wave-private 8KB slice, per-mf 2KB
    // sub-slice reused every 4 mf (same-wave DS ordering keeps it safe).
    __syncthreads();
    char* wbase = smem + w * 8192;
    const int rb = (lane >> 4) * 4;
    const int g4 = lane >> 4;
#pragma unroll
    for (int mf = 0; mf < 8; ++mf) {
      char* wmf = wbase + (mf & 3) * 2048;
#pragma unroll
      for (int nf = 0; nf < 4; ++nf) {
        float bv = (bias == nullptr) ? 0.f : bias[n0 + wn * 64 + nf * 16 + lr];
        int pb = nf ^ g4;
#pragma unroll
        for (int r = 0; r < 4; ++r)
          *(u16*)&wmf[(rb + r) * 128 + pb * 32 + lr * 2] =
              f2bf(acc[mf][nf][r] + bv);
      }
      asm volatile("s_waitcnt lgkmcnt(0)" ::: "memory");
      __builtin_amdgcn_sched_barrier(0);
      int rrow = lane >> 2, wb = lane & 3;
      int pb2 = wb ^ (rrow >> 2);
      short8 v0 = *(const short8*)&wmf[rrow * 128 + pb2 * 32];
      short8 v1 = *(const short8*)&wmf[rrow * 128 + pb2 * 32 + 16];
      size_t gidx = (size_t)(m0 + wm * 128 + mf * 16 + rrow) * ldOut +
                    (n0 + wn * 64 + wb * 16);
      if (EPI == 4) {
        short8 g0 = *(const short8*)&gate[gidx];
        short8 g1 = *(const short8*)&gate[gidx + 8];
        short8 o0, o1;
#pragma unroll
        for (int j = 0; j < 8; ++j) {
          o0[j] = (short)f2bf(bf2f((u16)v0[j]) * bf2f((u16)g0[j]));
          o1[j] = (short)f2bf(bf2f((u16)v1[j]) * bf2f((u16)g1[j]));
        }
        *(short8*)((u16*)Out + gidx) = o0;
        *(short8*)((u16*)Out + gidx + 8) = o1;
      } else {
        *(short8*)((u16*)Out + gidx) = v0;
        *(short8*)((u16*)Out + gidx + 8) = v1;
      }
      __builtin_amdgcn_sched_barrier(0);
    }
  }
}

// ---------- 128x128 m97-style GEMM -------------------------------------------
// EPI 0: f32 plain store to outs.p[blockIdx.z] (bias if non-null)
// EPI 1: bf16 + bias to outs.p[0] via LDS-staged coalesced store
template <int EPI>
__global__ __launch_bounds__(TB) void gemm_bt(
    const u16* __restrict__ A, int sA,
    const u16* __restrict__ Bw, int sB,
    const float* __restrict__ bias, Ptr8 outs,
    int ldOut, int Kext, int ksz) {
  __shared__ u16 As[128 * 32];
  __shared__ u16 Bs[128 * 32];
  const int tid = threadIdx.x, lane = tid & 63, w = tid >> 6;
  const int wr = w >> 1, wc = w & 1;
  int tx, ty; tile_xy(tx, ty);
  const int m0 = tx * 128, n0 = ty * 128;
  const int k0 = blockIdx.z * ksz;
  const int kend = min(k0 + ksz, Kext);

  f32x4 acc[4][4] = {};
  const int lr = lane & 15, lk = (lane >> 4) * 8;

  for (int kk = k0; kk < kend; kk += 32) {
#pragma unroll
    for (int is = 0; is < 2; ++is) {
      int c = is * 256 + tid;
      int r = c >> 2, kc = (c & 3) << 3;
      size_t lb = (size_t)(is * 256 + w * 64) * 8;
      gload16(A  + (size_t)(m0 + r) * sA + kk + kc, &As[lb]);
      gload16(Bw + (size_t)(n0 + r) * sB + kk + kc, &Bs[lb]);
    }
    __syncthreads();
    short8 af[4], bfv[4];
#pragma unroll
    for (int m = 0; m < 4; ++m)
      af[m] = *(const short8*)&As[(wr * 64 + m * 16 + lr) * 32 + lk];
#pragma unroll
    for (int n = 0; n < 4; ++n)
      bfv[n] = *(const short8*)&Bs[(wc * 64 + n * 16 + lr) * 32 + lk];
#pragma unroll
    for (int m = 0; m < 4; ++m)
#pragma unroll
      for (int n = 0; n < 4; ++n)
        acc[m][n] = __builtin_amdgcn_mfma_f32_16x16x32_bf16(af[m], bfv[n], acc[m][n], 0, 0, 0);
    __syncthreads();
  }

  if (EPI == 0) {
    float* Of = (float*)outs.p[blockIdx.z];
    const int rbase = (lane >> 4) * 4;
#pragma unroll
    for (int m = 0; m < 4; ++m) {
#pragma unroll
      for (int n = 0; n < 4; ++n) {
        int row0 = m0 + wr * 64 + m * 16 + rbase;
        int col  = n0 + wc * 64 + n * 16 + lr;
        float bv = (bias == nullptr) ? 0.f : bias[col];
#pragma unroll
        for (int r = 0; r < 4; ++r)
          Of[(size_t)(row0 + r) * ldOut + col] = acc[m][n][r] + bv;
      }
    }
  } else {
    // coalesced bf16 store: per-wave 4KB LDS slice, two 32-row halves.
    u16* Of = (u16*)outs.p[0];
    __syncthreads();
    char* slice = (w < 2) ? (char*)As + w * 4096 : (char*)Bs + (w - 2) * 4096;
    const int rb2 = (lane >> 4) * 4;
#pragma unroll
    for (int mh = 0; mh < 2; ++mh) {
#pragma unroll
      for (int mm = 0; mm < 2; ++mm) {
        int m = mh * 2 + mm;
#pragma unroll
        for (int n = 0; n < 4; ++n) {
          int col = n * 16 + lr;
          float bv = (bias == nullptr) ? 0.f : bias[n0 + wc * 64 + col];
#pragma unroll
          for (int r = 0; r < 4; ++r) {
            int rl = mm * 16 + rb2 + r;
            int bo = (col * 2) ^ ((rl & 7) << 4);
            *(u16*)&slice[rl * 128 + bo] = f2bf(acc[m][n][r] + bv);
          }
        }
      }
      asm volatile("s_waitcnt lgkmcnt(0)" ::: "memory");
      __builtin_amdgcn_sched_barrier(0);
#pragma unroll
      for (int s = 0; s < 4; ++s) {
        int c = s * 64 + lane;
        int rl = c >> 3;
        int bo = (((c & 7) ^ (rl & 7)) << 4);
        short8 v = *(const short8*)&slice[rl * 128 + bo];
        size_t grow = (size_t)(m0 + wr * 64 + mh * 32 + rl);
        *(short8*)&Of[grow * ldOut + n0 + wc * 64 + (c & 7) * 8] = v;
      }
      __builtin_amdgcn_sched_barrier(0);
    }
  }
}

// ---------- tier B fallback: f32-weight GEMMs (round-1 proven) ---------------
template <int EPI>
__global__ __launch_bounds__(TB) void gemm_wf32(
    const u16* __restrict__ A, int sA,
    const float* __restrict__ Bw, int sB,
    const float* __restrict__ bias, void* __restrict__ Out, int ldOut,
    int Kext, int ksz) {
  __shared__ u16 As[128 * 32];
  __shared__ u16 Bs[128 * 32];
  const int tid = threadIdx.x, lane = tid & 63, w = tid >> 6;
  const int wr = w >> 1, wc = w & 1;
  int tx, ty; tile_xy(tx, ty);
  const int m0 = tx * 128, n0 = ty * 128;
  const int k0 = blockIdx.z * ksz;
  const int kend = min(k0 + ksz, Kext);

  f32x4 acc[4][4] = {};
  const int lr = lane & 15, lk = (lane >> 4) * 8;

  for (int kk = k0; kk < kend; kk += 32) {
#pragma unroll
    for (int is = 0; is < 2; ++is) {
      int c = is * 256 + tid;
      int r = c >> 2, kc = (c & 3) << 3;
      gload16(A + (size_t)(m0 + r) * sA + kk + kc,
              &As[(size_t)(is * 256 + w * 64) * 8]);
    }
#pragma unroll
    for (int p = 0; p < 4; ++p) {
      int t = tid + p * 256;
      int r = t >> 3, c4 = (t & 7) << 2;
      float4 v = *(const float4*)&Bw[(size_t)(n0 + r) * sB + kk + c4];
      ushort4 o;
      o.x = f2bf(v.x); o.y = f2bf(v.y); o.z = f2bf(v.z); o.w = f2bf(v.w);
      *(ushort4*)&Bs[r * 32 + c4] = o;
    }
    __syncthreads();
    short8 af[4], bfv[4];
#pragma unroll
    for (int m = 0; m < 4; ++m)
      af[m] = *(const short8*)&As[(wr * 64 + m * 16 + lr) * 32 + lk];
#pragma unroll
    for (int n = 0; n < 4; ++n)
      bfv[n] = *(const short8*)&Bs[(wc * 64 + n * 16 + lr) * 32 + lk];
#pragma unroll
    for (int m = 0; m < 4; ++m)
#pragma unroll
      for (int n = 0; n < 4; ++n)
        acc[m][n] = __builtin_amdgcn_mfma_f32_16x16x32_bf16(af[m], bfv[n], acc[m][n], 0, 0, 0);
    __syncthreads();
  }

  const int rbase = (lane >> 4) * 4;
#pragma unroll
  for (int m = 0; m < 4; ++m) {
#pragma unroll
    for (int n = 0; n < 4; ++n) {
      int row0 = m0 + wr * 64 + m * 16 + rbase;
      int col  = n0 + wc * 64 + n * 16 + lr;
      float bv = (EPI == 3 || bias == nullptr) ? 0.f : bias[col];
#pragma unroll
      for (int r = 0; r < 4; ++r) {
        float v = acc[m][n][r] + bv;
        size_t idx = (size_t)(row0 + r) * ldOut + col;
        if (EPI == 0)      ((float*)Out)[idx] = v;
        else if (EPI == 1) ((u16*)Out)[idx] = f2bf(v);
        else if (EPI == 2) ((u16*)Out)[idx] = f2bf(v > 0.f ? v : 0.f);
        else               atomicAdd((float*)Out + idx, v);
      }
    }
  }
}

__global__ __launch_bounds__(TB) void gemm_dual_wf32(
    const u16* __restrict__ A1, const u16* __restrict__ A2, int sA,
    const float* __restrict__ B1, const float* __restrict__ B2, int sB,
    const float* __restrict__ bias1, const float* __restrict__ bias2,
    u16* __restrict__ Out, int ldOut, int K) {
  __shared__ u16 As1[128 * 32];
  __shared__ u16 As2[128 * 32];
  __shared__ u16 Bs1[128 * 32];
  __shared__ u16 Bs2[128 * 32];
  const int tid = threadIdx.x, lane = tid & 63, w = tid >> 6;
  const int wr = w >> 1, wc = w & 1;
  int tx, ty; tile_xy(tx, ty);
  const int m0 = tx * 128, n0 = ty * 128;

  f32x4 acc1[4][4] = {};
  f32x4 acc2[4][4] = {};
  const int lr = lane & 15, lk = (lane >> 4) * 8;

  for (int kk = 0; kk < K; kk += 32) {
#pragma unroll
    for (int is = 0; is < 2; ++is) {
      int c = is * 256 + tid;
      int r = c >> 2, kc = (c & 3) << 3;
      size_t lb = (size_t)(is * 256 + w * 64) * 8;
      gload16(A1 + (size_t)(m0 + r) * sA + kk + kc, &As1[lb]);
      gload16(A2 + (size_t)(m0 + r) * sA + kk + kc, &As2[lb]);
    }
#pragma unroll
    for (int p = 0; p < 4; ++p) {
      int t = tid + p * 256;
      int r = t >> 3, c4 = (t & 7) << 2;
      float4 v1 = *(const float4*)&B1[(size_t)(n0 + r) * sB + kk + c4];
      float4 v2 = *(const float4*)&B2[(size_t)(n0 + r) * sB + kk + c4];
      ushort4 o1, o2;
      o1.x = f2bf(v1.x); o1.y = f2bf(v1.y); o1.z = f2bf(v1.z); o1.w = f2bf(v1.w);
      o2.x = f2bf(v2.x); o2.y = f2bf(v2.y); o2.z = f2bf(v2.z); o2.w = f2bf(v2.w);
      *(ushort4*)&Bs1[r * 32 + c4] = o1;
      *(ushort4*)&Bs2[r * 32 + c4] = o2;
    }
    __syncthreads();
    short8 a1[4], a2[4], b1v[4], b2v[4];
#pragma unroll
    for (int m = 0; m < 4; ++m) {
      a1[m] = *(const short8*)&As1[(wr * 64 + m * 16 + lr) * 32 + lk];
      a2[m] = *(const short8*)&As2[(wr * 64 + m * 16 + lr) * 32 + lk];
    }
#pragma unroll
    for (int n = 0; n < 4; ++n) {
      b1v[n] = *(const short8*)&Bs1[(wc * 64 + n * 16 + lr) * 32 + lk];
      b2v[n] = *(const short8*)&Bs2[(wc * 64 + n * 16 + lr) * 32 + lk];
    }
#pragma unroll
    for (int m = 0; m < 4; ++m)
#pragma unroll
      for (int n = 0; n < 4; ++n) {
        acc1[m][n] = __builtin_amdgcn_mfma_f32_16x16x32_bf16(a1[m], b1v[n], acc1[m][n], 0, 0, 0);
        acc2[m][n] = __builtin_amdgcn_mfma_f32_16x16x32_bf16(a2[m], b2v[n], acc2[m][n], 0, 0, 0);
      }
    __syncthreads();
  }

  const int rbase = (lane >> 4) * 4;
#pragma unroll
  for (int m = 0; m < 4; ++m) {
#pragma unroll
    for (int n = 0; n < 4; ++n) {
      int row0 = m0 + wr * 64 + m * 16 + rbase;
      int col  = n0 + wc * 64 + n * 16 + lr;
      float bv1 = bias1[col], bv2 = bias2[col];
#pragma unroll
      for (int r = 0; r < 4; ++r) {
        float v = (acc1[m][n][r] + bv1) * (acc2[m][n][r] + bv2);
        Out[(size_t)(row0 + r) * ldOut + col] = f2bf(v);
      }
    }
  }
}

// ---------- LayerNorm over sum of ny partials (+preb) / attention -----------
template <int MODE>
__global__ __launch_bounds__(256) void resln_kernel(
    Ptr8 ys, int ny, const float* __restrict__ preb,
    const float* __restrict__ g, const float* __restrict__ bp,
    float* __restrict__ x, u16* __restrict__ xb,
    float* __restrict__ ctxo, int ctxRow) {
  const int r = blockIdx.x, tid = threadIdx.x;
  const size_t base = (size_t)r * 1024 + tid * 4;
  float y[4] = {0.f, 0.f, 0.f, 0.f};
  for (int j = 0; j < ny; ++j) {
    float4 z = *(const float4*)&((const float*)ys.p[j])[base];
    y[0] += z.x; y[1] += z.y; y[2] += z.z; y[3] += z.w;
  }
  if (preb != nullptr) {
    float4 p4 = *(const float4*)&preb[tid * 4];
    y[0] += p4.x; y[1] += p4.y; y[2] += p4.z; y[3] += p4.w;
  }
  float s = y[0] + y[1] + y[2] + y[3];
  float q = y[0] * y[0] + y[1] * y[1] + y[2] * y[2] + y[3] * y[3];
  __shared__ float red[8];
  for (int o = 32; o; o >>= 1) { s += __shfl_xor(s, o); q += __shfl_xor(q, o); }
  int wv = tid >> 6;
  if ((tid & 63) == 0) { red[wv] = s; red[4 + wv] = q; }
  __syncthreads();
  s = red[0] + red[1] + red[2] + red[3];
  q = red[4] + red[5] + red[6] + red[7];
  float mean = s * (1.f / 1024.f);
  float var  = q * (1.f / 1024.f) - mean * mean;
  float rs   = rsqrtf(var + 1e-5f);
  float4 g4 = *(const float4*)&g[tid * 4];
  float4 b4 = *(const float4*)&bp[tid * 4];
  float gg[4] = {g4.x, g4.y, g4.z, g4.w};
  float bb[4] = {b4.x, b4.y, b4.z, b4.w};
  float xv[4];
#pragma unroll
  for (int j = 0; j < 4; ++j) {
    float val = (y[j] - mean) * rs * gg[j] + bb[j];
    xv[j] = (MODE == 0) ? val : x[base + j] + val;
  }
  *(float4*)&x[base] = make_float4(xv[0], xv[1], xv[2], xv[3]);
  ushort4 xo;
  xo.x = f2bf(xv[0]); xo.y = f2bf(xv[1]); xo.z = f2bf(xv[2]); xo.w = f2bf(xv[3]);
  *(ushort4*)&xb[base] = xo;
  if (MODE != 1) {
    size_t cb = ((size_t)r * 4 + ctxRow) * 1024 + tid * 4;
    *(float4*)&ctxo[cb] = make_float4(xv[0], xv[1], xv[2], xv[3]);
  }
}

// tiny cross-attention; generalized strides (tier A split q/kv, tier B packed)
__global__ __launch_bounds__(64) void attn_kernel(
    const u16* __restrict__ q, int qstride,
    const u16* __restrict__ kv, int kvstride, int voff,
    u16* __restrict__ out, int L) {
  const int b = blockIdx.x >> 3, h = blockIdx.x & 7;
  const int lane = threadIdx.x;
  const size_t qoff = (size_t)b * qstride + h * 128;
  float q0 = bf2f(q[qoff + lane]);
  float q1 = bf2f(q[qoff + 64 + lane]);
  float sc[3];
  for (int l = 0; l < L; ++l) {
    size_t kb = ((size_t)l * B_ + b) * kvstride + h * 128;
    float p = q0 * bf2f(kv[kb + lane]) + q1 * bf2f(kv[kb + 64 + lane]);
    for (int o = 32; o; o >>= 1) p += __shfl_xor(p, o);
    sc[l] = p * 0.08838834764831843f;
  }
  float m = sc[0];
  for (int l = 1; l < L; ++l) m = fmaxf(m, sc[l]);
  float wsum = 0.f, wgt[3];
  for (int l = 0; l < L; ++l) { wgt[l] = expf(sc[l] - m); wsum += wgt[l]; }
  float inv = 1.f / wsum;
  float o0 = 0.f, o1 = 0.f;
  for (int l = 0; l < L; ++l) {
    size_t vb = ((size_t)l * B_ + b) * kvstride + voff + h * 128;
    o0 += wgt[l] * bf2f(kv[vb + lane]);
    o1 += wgt[l] * bf2f(kv[vb + 64 + lane]);
  }
  out[(size_t)b * 1024 + h * 128 + lane]      = f2bf(o0 * inv);
  out[(size_t)b * 1024 + h * 128 + 64 + lane] = f2bf(o1 * inv);
}

extern "C" void kernel_launch(void* const* d_in, const int* in_sizes, int n_in,
                              void* d_out, int out_size, void* d_ws, size_t ws_size,
                              hipStream_t stream) {
  (void)in_sizes; (void)n_in;
  const float* image = (const float*)d_in[0];
  const float* text  = (const float*)d_in[1];
  const float* fc1_w = (const float*)d_in[2];
  const float* fc1_b = (const float*)d_in[3];
  const float* fc2_w = (const float*)d_in[4];
  const float* fc2_b = (const float*)d_in[5];
  const float* fc3_w = (const float*)d_in[6];
  const float* fc3_b = (const float*)d_in[7];
  const float* ln_g  = (const float*)d_in[8];
  const float* ln_b  = (const float*)d_in[9];
  const float* Wqkv  = (const float*)d_in[10];
  const float* bqkv  = (const float*)d_in[11];
  const float* Wo    = (const float*)d_in[12];
  const float* bo    = (const float*)d_in[13];
  const float* W1    = (const float*)d_in[14];
  const float* b1    = (const float*)d_in[15];
  const float* W2    = (const float*)d_in[16];
  const float* b2    = (const float*)d_in[17];
  const float* n1_g  = (const float*)d_in[18];
  const float* n1_b  = (const float*)d_in[19];
  const float* n2_g  = (const float*)d_in[20];
  const float* n2_b  = (const float*)d_in[21];
  const float* WoutW = (const float*)d_in[22];
  const float* boutW = (const float*)d_in[23];

  float* outF   = (float*)d_out;
  float* ctxOut = outF + (size_t)B_ * DIN;
  char* ws = (char*)d_ws;

  auto cvt = [&](const float* s, u16* d, size_t n) {
    cvt_kernel<<<dim3((unsigned)((n + 1023) / 1024)), 256, 0, stream>>>(s, d, (int)n);
  };

  // ---------------- tier A: all-bf16 weights, atomic-free ------------------
  const size_t NEED_A = 232783872;  // ~222 MiB (proven to fit)
  if (ws_size >= NEED_A) {
    size_t off = 0;
    auto carve = [&](size_t bytes) -> char* {
      char* p = ws + off; off += (bytes + 255) & ~(size_t)255; return p;
    };
    u16* imgB  = (u16*)carve((size_t)B_ * DIN * 2);
    u16* txtB  = (u16*)carve((size_t)B_ * DIN * 2);
    u16* fc1B  = (u16*)carve((size_t)F * DIN * 2);   // dead after gated pass 2
    u16* fc2B  = (u16*)carve((size_t)F * DIN * 2);   // dead after gated pass 2
    u16* fc3B  = (u16*)carve((size_t)E * F * 2);
    u16* WqkvB = (u16*)carve((size_t)3 * E3 * E * 2);
    u16* WoB   = (u16*)carve((size_t)3 * E * E * 2);
    u16* W1B   = (u16*)carve((size_t)3 * E * E * 2);
    u16* W2B   = (u16*)carve((size_t)3 * E * E * 2);
    u16* WoutB = (u16*)carve((size_t)DIN * E * 2);
    char* U    = carve((size_t)B_ * F * 2);  // 64 MiB union region
    float* xF  = (float*)carve((size_t)B_ * E * 4);
    float* hF  = (float*)carve((size_t)B_ * E * 4);
    // fused phase: U holds fused[B, F] bf16, in-place gated
    u16* fusedB = (u16*)U;
    // post-fused overlay (fused dead after fc3)
    u16* kvB    = (u16*)(U);                   // [3*B, 2E] max 24 MiB
    u16* qB     = (u16*)(U + 25165824);        // [B, E] 4 MiB
    u16* ctxB   = (u16*)(U + 37748736);
    u16* attnB  = (u16*)(U + 37748736 + 16777216);
    u16* h1B    = (u16*)(U + 37748736 + 16777216 + 4194304);
    u16* xbB    = (u16*)(U + 37748736 + 16777216 + 8388608);
    // f32 partial scratch (8 MiB each) overlaying dead fc1B/fc2B
    float* PA = (float*)fc1B;
    float* PB = (float*)(fc1B + 4194304);
    float* PC = (float*)(fc1B + 8388608);
    float* PD = (float*)(fc1B + 12582912);
    float* PE = (float*)fc2B;
    float* PF = (float*)(fc2B + 4194304);

    cvt(image, imgB, (size_t)B_ * DIN);
    cvt(text,  txtB, (size_t)B_ * DIN);
    cvt(fc1_w, fc1B, (size_t)F * DIN);
    cvt(fc2_w, fc2B, (size_t)F * DIN);
    cvt(fc3_w, fc3B, (size_t)E * F);
    cvt(Wqkv,  WqkvB, (size_t)3 * E3 * E);
    cvt(Wo,    WoB,   (size_t)3 * E * E);
    cvt(W1,    W1B,   (size_t)3 * E * E);
    cvt(W2,    W2B,   (size_t)3 * E * E);
    cvt(WoutW, WoutB, (size_t)DIN * E);

    Ptr8 dumb{};
    // fused = txt@fc2^T + b2 (full F)
    gemm256<1><<<dim3(B_ / 256, F / 256), 512, 0, stream>>>(
        txtB, DIN, fc2B, DIN, fc2_b, nullptr, fusedB, dumb, F, DIN);
    // fused = (img@fc1^T + b1) * fused (in-place; fc1B/fc2B dead after)
    gemm256<4><<<dim3(B_ / 256, F / 256), 512, 0, stream>>>(
        imgB, DIN, fc1B, DIN, fc1_b, fusedB, fusedB, dumb, F, DIN);
    // fc3: 256-tile split-K=8 plain partials
    Ptr8 p8f{{xF, hF, PA, PB, PC, PD, PE, PF}};
    gemm256<0><<<dim3(B_ / 256, E / 256, 8), 512, 0, stream>>>(
        fusedB, F, fc3B, F, nullptr, nullptr, nullptr, p8f, E, F / 8);
    // x = LN(sum partials + fc3_b); ctx row 0
    resln_kernel<0><<<B_, 256, 0, stream>>>(
        p8f, 8, fc3_b, ln_g, ln_b, xF, ctxB, ctxOut, 0);

    Ptr8 p4{{hF, outF, PA, PB, nullptr, nullptr, nullptr, nullptr}};
    for (int i = 0; i < 3; ++i) {
      int L = i + 1;
      // KV for ctx rows 0..i: [L*B, 2E] with W rows E..3E of Wqkv[i]
      Ptr8 qkv1{{kvB, nullptr, nullptr, nullptr, nullptr, nullptr, nullptr, nullptr}};
      gemm_bt<1><<<dim3(L * B_ / 128, 2 * E / 128), TB, 0, stream>>>(
          ctxB, E, WqkvB + (size_t)i * E3 * E + (size_t)E * E, E,
          bqkv + (size_t)i * E3 + E, qkv1, 2 * E, E, E);
      // Q for newest row only
      Ptr8 qkv2{{qB, nullptr, nullptr, nullptr, nullptr, nullptr, nullptr, nullptr}};
      gemm_bt<1><<<dim3(B_ / 128, E / 128), TB, 0, stream>>>(
          ctxB + (size_t)i * B_ * E, E, WqkvB + (size_t)i * E3 * E, E,
          bqkv + (size_t)i * E3, qkv2, E, E, E);
      attn_kernel<<<B_ * 8, 64, 0, stream>>>(qB, E, kvB, 2 * E, E, attnB, L);
      // attn @ Wo^T: split-K=4 plain partials; bo folded into LN
      gemm_bt<0><<<dim3(B_ / 128, E / 128, 4), TB, 0, stream>>>(
          attnB, E, WoB + (size_t)i * E * E, E, nullptr, p4, E, E, E / 4);
      resln_kernel<1><<<B_, 256, 0, stream>>>(
          p4, 4, bo + (size_t)i * E, n1_g + (size_t)i * E, n1_b + (size_t)i * E,
          xF, xbB, nullptr, 0);
      // x @ W1^T: split-K=4; h1 = relu(sum + b1)
      gemm_bt<0><<<dim3(B_ / 128, E / 128, 4), TB, 0, stream>>>(
          xbB, E, W1B + (size_t)i * E * E, E, nullptr, p4, E, E, E / 4);
      relu_multi_kernel<<<B_ * E / 1024, 256, 0, stream>>>(
          p4, 4, b1 + (size_t)i * E, h1B);
      // h1 @ W2^T: split-K=4; b2 folded into LN
      gemm_bt<0><<<dim3(B_ / 128, E / 128, 4), TB, 0, stream>>>(
          h1B, E, W2B + (size_t)i * E * E, E, nullptr, p4, E, E, E / 4);
      resln_kernel<2><<<B_, 256, 0, stream>>>(
          p4, 4, b2 + (size_t)i * E, n2_g + (size_t)i * E, n2_b + (size_t)i * E,
          xF, ctxB + (size_t)(i + 1) * B_ * E, ctxOut, i + 1);
    }

    // final = x @ Wout^T: split-K=4 partials; combine + bout -> outF
    Ptr8 pfin{{hF, PA, PB, PC, nullptr, nullptr, nullptr, nullptr}};
    gemm_bt<0><<<dim3(B_ / 128, DIN / 128, 4), TB, 0, stream>>>(
        ctxB + (size_t)3 * B_ * E, E, WoutB, E, nullptr, pfin, DIN, E, E / 4);
    combine_out_kernel<<<B_ * DIN / 1024, 256, 0, stream>>>(pfin, 4, boutW, outF);
    return;
  }

  // ---------------- tier B: round-1 fallback (f32 weights, chunked) -------
  size_t off = 0;
  auto carve = [&](size_t bytes) -> char* {
    char* p = ws + off; off += (bytes + 255) & ~(size_t)255; return p;
  };
  u16* imgB   = (u16*)carve((size_t)B_ * DIN * 2);
  u16* txtB   = (u16*)carve((size_t)B_ * DIN * 2);
  u16* fusedC = (u16*)carve((size_t)B_ * CH * 2);
  u16* qkvB   = (u16*)carve((size_t)3 * B_ * E3 * 2);
  u16* ctxB   = (u16*)carve((size_t)4 * B_ * E * 2);
  u16* attnB  = (u16*)carve((size_t)B_ * E * 2);
  u16* h1B    = (u16*)carve((size_t)B_ * E * 2);
  u16* xbB    = (u16*)carve((size_t)B_ * E * 2);
  float* xF   = (float*)carve((size_t)B_ * E * 4);
  float* hF   = (float*)carve((size_t)B_ * E * 4);

  if (off > ws_size) {
    fill_kernel<<<(out_size + 255) / 256, 256, 0, stream>>>(outF, out_size, 12345.0f);
    return;
  }

  cvt(image, imgB, (size_t)B_ * DIN);
  cvt(text,  txtB, (size_t)B_ * DIN);
  hipMemsetAsync(hF, 0, (size_t)B_ * E * 4, stream);

  for (int c = 0; c < F / CH; ++c) {
    gemm_dual_wf32<<<dim3(B_ / 128, CH / 128), TB, 0, stream>>>(
        imgB, txtB, DIN,
        fc1_w + (size_t)c * CH * DIN, fc2_w + (size_t)c * CH * DIN, DIN,
        fc1_b + (size_t)c * CH, fc2_b + (size_t)c * CH, fusedC, CH, DIN);
    gemm_wf32<3><<<dim3(B_ / 128, E / 128, 2), TB, 0, stream>>>(
        fusedC, CH, fc3_w + (size_t)c * CH, F, nullptr, hF, E, CH, CH / 2);
  }
  {
    Ptr8 y1{{hF, nullptr, nullptr, nullptr, nullptr, nullptr, nullptr, nullptr}};
    resln_kernel<0><<<B_, 256, 0, stream>>>(y1, 1, fc3_b, ln_g, ln_b, xF, ctxB, ctxOut, 0);
  }

  for (int i = 0; i < 3; ++i) {
    int L = i + 1;
    gemm_wf32<1><<<dim3(L * B_ / 128, E3 / 128), TB, 0, stream>>>(
        ctxB, E, Wqkv + (size_t)i * E3 * E, E, bqkv + (size_t)i * E3, qkvB, E3, E, E);
    attn_kernel<<<B_ * 8, 64, 0, stream>>>(
        qkvB + (size_t)(L - 1) * B_ * E3, E3, qkvB + 1024, E3, 1024, attnB, L);
    gemm_wf32<0><<<dim3(B_ / 128, E / 128), TB, 0, stream>>>(
        attnB, E, Wo + (size_t)i * E * E, E, bo + (size_t)i * E, hF, E, E, E);
    Ptr8 y1{{hF, nullptr, nullptr, nullptr, nullptr, nullptr, nullptr, nullptr}};
    resln_kernel<1><<<B_, 256, 0, stream>>>(
        y1, 1, nullptr, n1_g + (size_t)i * E, n1_b + (size_t)i * E, xF, xbB, nullptr, 0);
    gemm_wf32<2><<<dim3(B_ / 128, E / 128), TB, 0, stream>>>(
        xbB, E, W1 + (size_t)i * E * E, E, b1 + (size_t)i * E, h1B, E, E, E);
    gemm_wf32<0><<<dim3(B_ / 128, E / 128), TB, 0, stream>>>(
        h1B, E, W2 + (size_t)i * E * E, E, b2 + (size_t)i * E, hF, E, E, E);
    resln_kernel<2><<<B_, 256, 0, stream>>>(
        y1, 1, nullptr, n2_g + (size_t)i * E, n2_b + (size_t)i * E, xF,
        ctxB + (size_t)(i + 1) * B_ * E, ctxOut, i + 1);
  }
  gemm_wf32<0><<<dim3(B_ / 128, DIN / 128), TB, 0, stream>>>(
      ctxB + (size_t)3 * B_ * E, E, WoutW, E, boutW, outF, DIN, E, E);
}

// Round 16
// 835.644 us; speedup vs baseline: 3.2663x; 3.2663x over previous
//
#include <hip/hip_runtime.h>

#define TB 256

typedef __attribute__((ext_vector_type(8))) short short8;
typedef __attribute__((ext_vector_type(4))) float f32x4;
typedef unsigned short u16;

constexpr int B_  = 2048;
constexpr int DIN = 1024;
constexpr int E   = 1024;
constexpr int F   = 16384;
constexpr int E3  = 3072;
constexpr int CH  = 4096;  // tier-B chunk

struct Ptr8 { void* p[8]; };

__device__ __forceinline__ u16 f2bf(float f) {
  union { float f; unsigned u; } v; v.f = f;
  unsigned r = v.u + 0x7fffu + ((v.u >> 16) & 1u);
  return (u16)(r >> 16);
}
__device__ __forceinline__ float bf2f(u16 u) {
  union { unsigned u; float f; } v; v.u = ((unsigned)u) << 16;
  return v.f;
}

__device__ __forceinline__ void gload16(const void* g, void* l) {
  __builtin_amdgcn_global_load_lds(
      (const __attribute__((address_space(1))) void*)g,
      (__attribute__((address_space(3))) void*)l, 16, 0, 0);
}

// XCD-aware tile swizzle (bijective when nwg % 8 == 0; else identity)
__device__ __forceinline__ void tile_xy(int& tx, int& ty) {
  int gx = gridDim.x;
  int nwg = gx * gridDim.y;
  int wg = blockIdx.y * gx + blockIdx.x;
  if ((nwg & 7) == 0) wg = (wg & 7) * (nwg >> 3) + (wg >> 3);
  tx = wg % gx; ty = wg / gx;
}

// LDS byte-offset swizzle within a 32 KB operand tile (256 rows x 128 B)
__device__ __forceinline__ int swz16(int o) {
  return o ^ (((o >> 7) & 7) << 4);
}

__global__ __launch_bounds__(256) void cvt_kernel(const float* __restrict__ s,
                                                  u16* __restrict__ d, int n) {
  int i = (blockIdx.x * 256 + threadIdx.x) * 4;
  if (i >= n) return;
  float4 v = *(const float4*)&s[i];
  ushort4 o;
  o.x = f2bf(v.x); o.y = f2bf(v.y); o.z = f2bf(v.z); o.w = f2bf(v.w);
  *(ushort4*)&d[i] = o;
}

__global__ __launch_bounds__(256) void fill_kernel(float* p, int n, float v) {
  int i = blockIdx.x * 256 + threadIdx.x;
  if (i < n) p[i] = v;
}

// out_bf16 = relu(sum_{j<ny} Y[j] + bias[col])
__global__ __launch_bounds__(256) void relu_multi_kernel(
    Ptr8 ys, int ny, const float* __restrict__ bias, u16* __restrict__ out) {
  size_t i = ((size_t)blockIdx.x * 256 + threadIdx.x) * 4;
  int col = (int)(i & 1023);
  float4 b = *(const float4*)&bias[col];
  float a0 = b.x, a1 = b.y, a2 = b.z, a3 = b.w;
  for (int j = 0; j < ny; ++j) {
    float4 z = *(const float4*)&((const float*)ys.p[j])[i];
    a0 += z.x; a1 += z.y; a2 += z.z; a3 += z.w;
  }
  ushort4 o;
  o.x = f2bf(a0 > 0.f ? a0 : 0.f);
  o.y = f2bf(a1 > 0.f ? a1 : 0.f);
  o.z = f2bf(a2 > 0.f ? a2 : 0.f);
  o.w = f2bf(a3 > 0.f ? a3 : 0.f);
  *(ushort4*)&out[i] = o;
}

// out_f32 = sum_{j<ny} Y[j] + bias[col]   (final Wout combine)
__global__ __launch_bounds__(256) void combine_out_kernel(
    Ptr8 ys, int ny, const float* __restrict__ bias, float* __restrict__ out) {
  size_t i = ((size_t)blockIdx.x * 256 + threadIdx.x) * 4;
  int col = (int)(i & 1023);
  float4 b = *(const float4*)&bias[col];
  float a0 = b.x, a1 = b.y, a2 = b.z, a3 = b.w;
  for (int j = 0; j < ny; ++j) {
    float4 z = *(const float4*)&((const float*)ys.p[j])[i];
    a0 += z.x; a1 += z.y; a2 += z.z; a3 += z.w;
  }
  out[i] = a0; out[i + 1] = a1; out[i + 2] = a2; out[i + 3] = a3;
}

// ======= 256x256 bf16 GEMM, 2-phase double-buffer (round-11 proven) =========
// EPI: 0 f32 plain store to pouts.p[blockIdx.z] (split-K), 1 bf16+bias,
//      4 gated bf16 in-place (gate may alias Out; same-element RMW).
// EPI 1/4 use the LDS-staged fully-coalesced store path.
template <int EPI>
__global__ __launch_bounds__(512, 2) void gemm256(
    const u16* __restrict__ A, int sA,
    const u16* __restrict__ Bw, int sB,
    const float* __restrict__ bias, const u16* __restrict__ gate,
    void* __restrict__ Out, Ptr8 pouts, int ldOut, int ksz) {
  __shared__ __align__(16) char smem[131072];
  const int tid = threadIdx.x, lane = tid & 63, w = tid >> 6;
  const int wm = w >> 2, wn = w & 3;
  int tx, ty; tile_xy(tx, ty);
  const int m0 = tx * 256, n0 = ty * 256;
  const int k0 = blockIdx.z * ksz;
  const int nt = ksz >> 6;
  const int lr = lane & 15;

  f32x4 acc[8][4] = {};

  auto stage = [&](const u16* __restrict__ G, int gs, int gr0, int kk, int tb, int j) {
    int P = j * 8192 + w * 1024 + lane * 16;
    int L = swz16(P);
    int row = L >> 7, colb = L & 127;
    gload16(G + (size_t)(gr0 + row) * gs + kk + (colb >> 1),
            &smem[tb + P]);
  };
  auto rdA = [&](int tb, int mf, int kh) -> short8 {
    int Lo = (wm * 128 + mf * 16 + lr) * 128 + kh * 64 + (lane >> 4) * 16;
    return *(const short8*)&smem[tb + swz16(Lo)];
  };
  auto rdB = [&](int tb, int nf, int kh) -> short8 {
    int Lo = (wn * 64 + nf * 16 + lr) * 128 + kh * 64 + (lane >> 4) * 16;
    return *(const short8*)&smem[tb + swz16(Lo)];
  };

#pragma unroll
  for (int j = 0; j < 4; ++j) stage(A, sA, m0, k0, 0, j);
#pragma unroll
  for (int j = 0; j < 4; ++j) stage(Bw, sB, n0, k0, 65536, j);
  asm volatile("s_waitcnt vmcnt(0)" ::: "memory");
  __builtin_amdgcn_sched_barrier(0);
  __builtin_amdgcn_s_barrier();

  int cur = 0;
  for (int t = 0; t < nt; ++t) {
    const int sa = cur * 32768;
    const int sb = 65536 + cur * 32768;
    if (t + 1 < nt) {
      const int sa2 = (cur ^ 1) * 32768;
      const int sb2 = 65536 + (cur ^ 1) * 32768;
#pragma unroll
      for (int j = 0; j < 4; ++j) stage(A, sA, m0, k0 + (t + 1) * 64, sa2, j);
#pragma unroll
      for (int j = 0; j < 4; ++j) stage(Bw, sB, n0, k0 + (t + 1) * 64, sb2, j);
    }
    short8 bfr[4][2], afr[4][2];
#pragma unroll
    for (int nf = 0; nf < 4; ++nf)
#pragma unroll
      for (int kh = 0; kh < 2; ++kh) bfr[nf][kh] = rdB(sb, nf, kh);
#pragma unroll
    for (int mf = 0; mf < 4; ++mf)
#pragma unroll
      for (int kh = 0; kh < 2; ++kh) afr[mf][kh] = rdA(sa, mf, kh);
    __builtin_amdgcn_s_setprio(1);
#pragma unroll
    for (int mf = 0; mf < 4; ++mf)
#pragma unroll
      for (int nf = 0; nf < 4; ++nf)
#pragma unroll
        for (int kh = 0; kh < 2; ++kh)
          acc[mf][nf] = __builtin_amdgcn_mfma_f32_16x16x32_bf16(
              afr[mf][kh], bfr[nf][kh], acc[mf][nf], 0, 0, 0);
    __builtin_amdgcn_s_setprio(0);
#pragma unroll
    for (int mf = 0; mf < 4; ++mf)
#pragma unroll
      for (int kh = 0; kh < 2; ++kh) afr[mf][kh] = rdA(sa, 4 + mf, kh);
    __builtin_amdgcn_s_setprio(1);
#pragma unroll
    for (int mf = 0; mf < 4; ++mf)
#pragma unroll
      for (int nf = 0; nf < 4; ++nf)
#pragma unroll
        for (int kh = 0; kh < 2; ++kh)
          acc[4 + mf][nf] = __builtin_amdgcn_mfma_f32_16x16x32_bf16(
              afr[mf][kh], bfr[nf][kh], acc[4 + mf][nf], 0, 0, 0);
    __builtin_amdgcn_s_setprio(0);
    if (t + 1 < nt) {
      asm volatile("s_waitcnt vmcnt(0)" ::: "memory");
      __builtin_amdgcn_sched_barrier(0);
      __builtin_amdgcn_s_barrier();
    }
    cur ^= 1;
  }

  if (EPI == 0) {
    float* Pf = (float*)pouts.p[blockIdx.z];
    const int rb = (lane >> 4) * 4;
#pragma unroll
    for (int mf = 0; mf < 8; ++mf) {
#pragma unroll
      for (int nf = 0; nf < 4; ++nf) {
        int row0 = m0 + wm * 128 + mf * 16 + rb;
        int col  = n0 + wn * 64 + nf * 16 + lr;
#pragma unroll
        for (int r = 0; r < 4; ++r)
          Pf[(size_t)(row0 + r) * ldOut + col] = acc[mf][nf][r];
      }
    }
  } else {
    // LDS-staged coalesced bf16 store path (wave-private 16KB slice).
    __syncthreads();
    char* wbase = smem + w * 16384;
    const int rb = (lane >> 4) * 4;
    const int g4 = lane >> 4;
#pragma unroll
    for (int mf = 0; mf < 8; ++mf) {
      char* wmf = wbase + mf * 2048;
#pragma unroll
      for (int nf = 0; nf < 4; ++nf) {
        float bv = (bias == nullptr) ? 0.f : bias[n0 + wn * 64 + nf * 16 + lr];
        int pb = nf ^ g4;
#pragma unroll
        for (int r = 0; r < 4; ++r)
          *(u16*)&wmf[(rb + r) * 128 + pb * 32 + lr * 2] =
              f2bf(acc[mf][nf][r] + bv);
      }
      asm volatile("s_waitcnt lgkmcnt(0)" ::: "memory");
      __builtin_amdgcn_sched_barrier(0);
      int rrow = lane >> 2, wb = lane & 3;
      int pb2 = wb ^ (rrow >> 2);
      short8 v0 = *(const short8*)&wmf[rrow * 128 + pb2 * 32];
      short8 v1 = *(const short8*)&wmf[rrow * 128 + pb2 * 32 + 16];
      size_t gidx = (size_t)(m0 + wm * 128 + mf * 16 + rrow) * ldOut +
                    (n0 + wn * 64 + wb * 16);
      if (EPI == 4) {
        short8 g0 = *(const short8*)&gate[gidx];
        short8 g1 = *(const short8*)&gate[gidx + 8];
        short8 o0, o1;
#pragma unroll
        for (int j = 0; j < 8; ++j) {
          o0[j] = (short)f2bf(bf2f((u16)v0[j]) * bf2f((u16)g0[j]));
          o1[j] = (short)f2bf(bf2f((u16)v1[j]) * bf2f((u16)g1[j]));
        }
        *(short8*)((u16*)Out + gidx) = o0;
        *(short8*)((u16*)Out + gidx + 8) = o1;
      } else {
        *(short8*)((u16*)Out + gidx) = v0;
        *(short8*)((u16*)Out + gidx + 8) = v1;
      }
    }
  }
}

// ---------- 128x128 m97-style GEMM -------------------------------------------
// EPI 0: f32 plain store to outs.p[blockIdx.z] (bias if non-null)
// EPI 1: bf16 + bias to outs.p[0] via LDS-staged coalesced store
template <int EPI>
__global__ __launch_bounds__(TB) void gemm_bt(
    const u16* __restrict__ A, int sA,
    const u16* __restrict__ Bw, int sB,
    const float* __restrict__ bias, Ptr8 outs,
    int ldOut, int Kext, int ksz) {
  __shared__ u16 As[128 * 32];
  __shared__ u16 Bs[128 * 32];
  const int tid = threadIdx.x, lane = tid & 63, w = tid >> 6;
  const int wr = w >> 1, wc = w & 1;
  int tx, ty; tile_xy(tx, ty);
  const int m0 = tx * 128, n0 = ty * 128;
  const int k0 = blockIdx.z * ksz;
  const int kend = min(k0 + ksz, Kext);

  f32x4 acc[4][4] = {};
  const int lr = lane & 15, lk = (lane >> 4) * 8;

  for (int kk = k0; kk < kend; kk += 32) {
#pragma unroll
    for (int is = 0; is < 2; ++is) {
      int c = is * 256 + tid;
      int r = c >> 2, kc = (c & 3) << 3;
      size_t lb = (size_t)(is * 256 + w * 64) * 8;
      gload16(A  + (size_t)(m0 + r) * sA + kk + kc, &As[lb]);
      gload16(Bw + (size_t)(n0 + r) * sB + kk + kc, &Bs[lb]);
    }
    __syncthreads();
    short8 af[4], bfv[4];
#pragma unroll
    for (int m = 0; m < 4; ++m)
      af[m] = *(const short8*)&As[(wr * 64 + m * 16 + lr) * 32 + lk];
#pragma unroll
    for (int n = 0; n < 4; ++n)
      bfv[n] = *(const short8*)&Bs[(wc * 64 + n * 16 + lr) * 32 + lk];
#pragma unroll
    for (int m = 0; m < 4; ++m)
#pragma unroll
      for (int n = 0; n < 4; ++n)
        acc[m][n] = __builtin_amdgcn_mfma_f32_16x16x32_bf16(af[m], bfv[n], acc[m][n], 0, 0, 0);
    __syncthreads();
  }

  if (EPI == 0) {
    float* Of = (float*)outs.p[blockIdx.z];
    const int rbase = (lane >> 4) * 4;
#pragma unroll
    for (int m = 0; m < 4; ++m) {
#pragma unroll
      for (int n = 0; n < 4; ++n) {
        int row0 = m0 + wr * 64 + m * 16 + rbase;
        int col  = n0 + wc * 64 + n * 16 + lr;
        float bv = (bias == nullptr) ? 0.f : bias[col];
#pragma unroll
        for (int r = 0; r < 4; ++r)
          Of[(size_t)(row0 + r) * ldOut + col] = acc[m][n][r] + bv;
      }
    }
  } else {
    // coalesced bf16 store: per-wave 4KB LDS slice, two 32-row halves.
    u16* Of = (u16*)outs.p[0];
    __syncthreads();
    char* slice = (w < 2) ? (char*)As + w * 4096 : (char*)Bs + (w - 2) * 4096;
    const int rb2 = (lane >> 4) * 4;
#pragma unroll
    for (int mh = 0; mh < 2; ++mh) {
#pragma unroll
      for (int mm = 0; mm < 2; ++mm) {
        int m = mh * 2 + mm;
#pragma unroll
        for (int n = 0; n < 4; ++n) {
          int col = n * 16 + lr;
          float bv = (bias == nullptr) ? 0.f : bias[n0 + wc * 64 + col];
#pragma unroll
          for (int r = 0; r < 4; ++r) {
            int rl = mm * 16 + rb2 + r;
            int bo = (col * 2) ^ ((rl & 7) << 4);
            *(u16*)&slice[rl * 128 + bo] = f2bf(acc[m][n][r] + bv);
          }
        }
      }
      asm volatile("s_waitcnt lgkmcnt(0)" ::: "memory");
      __builtin_amdgcn_sched_barrier(0);
#pragma unroll
      for (int s = 0; s < 4; ++s) {
        int c = s * 64 + lane;
        int rl = c >> 3;
        int bo = (((c & 7) ^ (rl & 7)) << 4);
        short8 v = *(const short8*)&slice[rl * 128 + bo];
        size_t grow = (size_t)(m0 + wr * 64 + mh * 32 + rl);
        *(short8*)&Of[grow * ldOut + n0 + wc * 64 + (c & 7) * 8] = v;
      }
      __builtin_amdgcn_sched_barrier(0);
    }
  }
}

// ---------- tier B fallback: f32-weight GEMMs (round-1 proven) ---------------
template <int EPI>
__global__ __launch_bounds__(TB) void gemm_wf32(
    const u16* __restrict__ A, int sA,
    const float* __restrict__ Bw, int sB,
    const float* __restrict__ bias, void* __restrict__ Out, int ldOut,
    int Kext, int ksz) {
  __shared__ u16 As[128 * 32];
  __shared__ u16 Bs[128 * 32];
  const int tid = threadIdx.x, lane = tid & 63, w = tid >> 6;
  const int wr = w >> 1, wc = w & 1;
  int tx, ty; tile_xy(tx, ty);
  const int m0 = tx * 128, n0 = ty * 128;
  const int k0 = blockIdx.z * ksz;
  const int kend = min(k0 + ksz, Kext);

  f32x4 acc[4][4] = {};
  const int lr = lane & 15, lk = (lane >> 4) * 8;

  for (int kk = k0; kk < kend; kk += 32) {
#pragma unroll
    for (int is = 0; is < 2; ++is) {
      int c = is * 256 + tid;
      int r = c >> 2, kc = (c & 3) << 3;
      gload16(A + (size_t)(m0 + r) * sA + kk + kc,
              &As[(size_t)(is * 256 + w * 64) * 8]);
    }
#pragma unroll
    for (int p = 0; p < 4; ++p) {
      int t = tid + p * 256;
      int r = t >> 3, c4 = (t & 7) << 2;
      float4 v = *(const float4*)&Bw[(size_t)(n0 + r) * sB + kk + c4];
      ushort4 o;
      o.x = f2bf(v.x); o.y = f2bf(v.y); o.z = f2bf(v.z); o.w = f2bf(v.w);
      *(ushort4*)&Bs[r * 32 + c4] = o;
    }
    __syncthreads();
    short8 af[4], bfv[4];
#pragma unroll
    for (int m = 0; m < 4; ++m)
      af[m] = *(const short8*)&As[(wr * 64 + m * 16 + lr) * 32 + lk];
#pragma unroll
    for (int n = 0; n < 4; ++n)
      bfv[n] = *(const short8*)&Bs[(wc * 64 + n * 16 + lr) * 32 + lk];
#pragma unroll
    for (int m = 0; m < 4; ++m)
#pragma unroll
      for (int n = 0; n < 4; ++n)
        acc[m][n] = __builtin_amdgcn_mfma_f32_16x16x32_bf16(af[m], bfv[n], acc[m][n], 0, 0, 0);
    __syncthreads();
  }

  const int rbase = (lane >> 4) * 4;
#pragma unroll
  for (int m = 0; m < 4; ++m) {
#pragma unroll
    for (int n = 0; n < 4; ++n) {
      int row0 = m0 + wr * 64 + m * 16 + rbase;
      int col  = n0 + wc * 64 + n * 16 + lr;
      float bv = (EPI == 3 || bias == nullptr) ? 0.f : bias[col];
#pragma unroll
      for (int r = 0; r < 4; ++r) {
        float v = acc[m][n][r] + bv;
        size_t idx = (size_t)(row0 + r) * ldOut + col;
        if (EPI == 0)      ((float*)Out)[idx] = v;
        else if (EPI == 1) ((u16*)Out)[idx] = f2bf(v);
        else if (EPI == 2) ((u16*)Out)[idx] = f2bf(v > 0.f ? v : 0.f);
        else               atomicAdd((float*)Out + idx, v);
      }
    }
  }
}

__global__ __launch_bounds__(TB) void gemm_dual_wf32(
    const u16* __restrict__ A1, const u16* __restrict__ A2, int sA,
    const float* __restrict__ B1, const float* __restrict__ B2, int sB,
    const float* __restrict__ bias1, const float* __restrict__ bias2,
    u16* __restrict__ Out, int ldOut, int K) {
  __shared__ u16 As1[128 * 32];
  __shared__ u16 As2[128 * 32];
  __shared__ u16 Bs1[128 * 32];
  __shared__ u16 Bs2[128 * 32];
  const int tid = threadIdx.x, lane = tid & 63, w = tid >> 6;
  const int wr = w >> 1, wc = w & 1;
  int tx, ty; tile_xy(tx, ty);
  const int m0 = tx * 128, n0 = ty * 128;

  f32x4 acc1[4][4] = {};
  f32x4 acc2[4][4] = {};
  const int lr = lane & 15, lk = (lane >> 4) * 8;

  for (int kk = 0; kk < K; kk += 32) {
#pragma unroll
    for (int is = 0; is < 2; ++is) {
      int c = is * 256 + tid;
      int r = c >> 2, kc = (c & 3) << 3;
      size_t lb = (size_t)(is * 256 + w * 64) * 8;
      gload16(A1 + (size_t)(m0 + r) * sA + kk + kc, &As1[lb]);
      gload16(A2 + (size_t)(m0 + r) * sA + kk + kc, &As2[lb]);
    }
#pragma unroll
    for (int p = 0; p < 4; ++p) {
      int t = tid + p * 256;
      int r = t >> 3, c4 = (t & 7) << 2;
      float4 v1 = *(const float4*)&B1[(size_t)(n0 + r) * sB + kk + c4];
      float4 v2 = *(const float4*)&B2[(size_t)(n0 + r) * sB + kk + c4];
      ushort4 o1, o2;
      o1.x = f2bf(v1.x); o1.y = f2bf(v1.y); o1.z = f2bf(v1.z); o1.w = f2bf(v1.w);
      o2.x = f2bf(v2.x); o2.y = f2bf(v2.y); o2.z = f2bf(v2.z); o2.w = f2bf(v2.w);
      *(ushort4*)&Bs1[r * 32 + c4] = o1;
      *(ushort4*)&Bs2[r * 32 + c4] = o2;
    }
    __syncthreads();
    short8 a1[4], a2[4], b1v[4], b2v[4];
#pragma unroll
    for (int m = 0; m < 4; ++m) {
      a1[m] = *(const short8*)&As1[(wr * 64 + m * 16 + lr) * 32 + lk];
      a2[m] = *(const short8*)&As2[(wr * 64 + m * 16 + lr) * 32 + lk];
    }
#pragma unroll
    for (int n = 0; n < 4; ++n) {
      b1v[n] = *(const short8*)&Bs1[(wc * 64 + n * 16 + lr) * 32 + lk];
      b2v[n] = *(const short8*)&Bs2[(wc * 64 + n * 16 + lr) * 32 + lk];
    }
#pragma unroll
    for (int m = 0; m < 4; ++m)
#pragma unroll
      for (int n = 0; n < 4; ++n) {
        acc1[m][n] = __builtin_amdgcn_mfma_f32_16x16x32_bf16(a1[m], b1v[n], acc1[m][n], 0, 0, 0);
        acc2[m][n] = __builtin_amdgcn_mfma_f32_16x16x32_bf16(a2[m], b2v[n], acc2[m][n], 0, 0, 0);
      }
    __syncthreads();
  }

  const int rbase = (lane >> 4) * 4;
#pragma unroll
  for (int m = 0; m < 4; ++m) {
#pragma unroll
    for (int n = 0; n < 4; ++n) {
      int row0 = m0 + wr * 64 + m * 16 + rbase;
      int col  = n0 + wc * 64 + n * 16 + lr;
      float bv1 = bias1[col], bv2 = bias2[col];
#pragma unroll
      for (int r = 0; r < 4; ++r) {
        float v = (acc1[m][n][r] + bv1) * (acc2[m][n][r] + bv2);
        Out[(size_t)(row0 + r) * ldOut + col] = f2bf(v);
      }
    }
  }
}

// ---------- LayerNorm over sum of ny partials (+preb) / attention -----------
template <int MODE>
__global__ __launch_bounds__(256) void resln_kernel(
    Ptr8 ys, int ny, const float* __restrict__ preb,
    const float* __restrict__ g, const float* __restrict__ bp,
    float* __restrict__ x, u16* __restrict__ xb,
    float* __restrict__ ctxo, int ctxRow) {
  const int r = blockIdx.x, tid = threadIdx.x;
  const size_t base = (size_t)r * 1024 + tid * 4;
  float y[4] = {0.f, 0.f, 0.f, 0.f};
  for (int j = 0; j < ny; ++j) {
    float4 z = *(const float4*)&((const float*)ys.p[j])[base];
    y[0] += z.x; y[1] += z.y; y[2] += z.z; y[3] += z.w;
  }
  if (preb != nullptr) {
    float4 p4 = *(const float4*)&preb[tid * 4];
    y[0] += p4.x; y[1] += p4.y; y[2] += p4.z; y[3] += p4.w;
  }
  float s = y[0] + y[1] + y[2] + y[3];
  float q = y[0] * y[0] + y[1] * y[1] + y[2] * y[2] + y[3] * y[3];
  __shared__ float red[8];
  for (int o = 32; o; o >>= 1) { s += __shfl_xor(s, o); q += __shfl_xor(q, o); }
  int wv = tid >> 6;
  if ((tid & 63) == 0) { red[wv] = s; red[4 + wv] = q; }
  __syncthreads();
  s = red[0] + red[1] + red[2] + red[3];
  q = red[4] + red[5] + red[6] + red[7];
  float mean = s * (1.f / 1024.f);
  float var  = q * (1.f / 1024.f) - mean * mean;
  float rs   = rsqrtf(var + 1e-5f);
  float4 g4 = *(const float4*)&g[tid * 4];
  float4 b4 = *(const float4*)&bp[tid * 4];
  float gg[4] = {g4.x, g4.y, g4.z, g4.w};
  float bb[4] = {b4.x, b4.y, b4.z, b4.w};
  float xv[4];
#pragma unroll
  for (int j = 0; j < 4; ++j) {
    float val = (y[j] - mean) * rs * gg[j] + bb[j];
    xv[j] = (MODE == 0) ? val : x[base + j] + val;
  }
  *(float4*)&x[base] = make_float4(xv[0], xv[1], xv[2], xv[3]);
  ushort4 xo;
  xo.x = f2bf(xv[0]); xo.y = f2bf(xv[1]); xo.z = f2bf(xv[2]); xo.w = f2bf(xv[3]);
  *(ushort4*)&xb[base] = xo;
  if (MODE != 1) {
    size_t cb = ((size_t)r * 4 + ctxRow) * 1024 + tid * 4;
    *(float4*)&ctxo[cb] = make_float4(xv[0], xv[1], xv[2], xv[3]);
  }
}

// tiny cross-attention; generalized strides (tier A split q/kv, tier B packed)
__global__ __launch_bounds__(64) void attn_kernel(
    const u16* __restrict__ q, int qstride,
    const u16* __restrict__ kv, int kvstride, int voff,
    u16* __restrict__ out, int L) {
  const int b = blockIdx.x >> 3, h = blockIdx.x & 7;
  const int lane = threadIdx.x;
  const size_t qoff = (size_t)b * qstride + h * 128;
  float q0 = bf2f(q[qoff + lane]);
  float q1 = bf2f(q[qoff + 64 + lane]);
  float sc[3];
  for (int l = 0; l < L; ++l) {
    size_t kb = ((size_t)l * B_ + b) * kvstride + h * 128;
    float p = q0 * bf2f(kv[kb + lane]) + q1 * bf2f(kv[kb + 64 + lane]);
    for (int o = 32; o; o >>= 1) p += __shfl_xor(p, o);
    sc[l] = p * 0.08838834764831843f;
  }
  float m = sc[0];
  for (int l = 1; l < L; ++l) m = fmaxf(m, sc[l]);
  float wsum = 0.f, wgt[3];
  for (int l = 0; l < L; ++l) { wgt[l] = expf(sc[l] - m); wsum += wgt[l]; }
  float inv = 1.f / wsum;
  float o0 = 0.f, o1 = 0.f;
  for (int l = 0; l < L; ++l) {
    size_t vb = ((size_t)l * B_ + b) * kvstride + voff + h * 128;
    o0 += wgt[l] * bf2f(kv[vb + lane]);
    o1 += wgt[l] * bf2f(kv[vb + 64 + lane]);
  }
  out[(size_t)b * 1024 + h * 128 + lane]      = f2bf(o0 * inv);
  out[(size_t)b * 1024 + h * 128 + 64 + lane] = f2bf(o1 * inv);
}

extern "C" void kernel_launch(void* const* d_in, const int* in_sizes, int n_in,
                              void* d_out, int out_size, void* d_ws, size_t ws_size,
                              hipStream_t stream) {
  (void)in_sizes; (void)n_in;
  const float* image = (const float*)d_in[0];
  const float* text  = (const float*)d_in[1];
  const float* fc1_w = (const float*)d_in[2];
  const float* fc1_b = (const float*)d_in[3];
  const float* fc2_w = (const float*)d_in[4];
  const float* fc2_b = (const float*)d_in[5];
  const float* fc3_w = (const float*)d_in[6];
  const float* fc3_b = (const float*)d_in[7];
  const float* ln_g  = (const float*)d_in[8];
  const float* ln_b  = (const float*)d_in[9];
  const float* Wqkv  = (const float*)d_in[10];
  const float* bqkv  = (const float*)d_in[11];
  const float* Wo    = (const float*)d_in[12];
  const float* bo    = (const float*)d_in[13];
  const float* W1    = (const float*)d_in[14];
  const float* b1    = (const float*)d_in[15];
  const float* W2    = (const float*)d_in[16];
  const float* b2    = (const float*)d_in[17];
  const float* n1_g  = (const float*)d_in[18];
  const float* n1_b  = (const float*)d_in[19];
  const float* n2_g  = (const float*)d_in[20];
  const float* n2_b  = (const float*)d_in[21];
  const float* WoutW = (const float*)d_in[22];
  const float* boutW = (const float*)d_in[23];

  float* outF   = (float*)d_out;
  float* ctxOut = outF + (size_t)B_ * DIN;
  char* ws = (char*)d_ws;

  auto cvt = [&](const float* s, u16* d, size_t n) {
    cvt_kernel<<<dim3((unsigned)((n + 1023) / 1024)), 256, 0, stream>>>(s, d, (int)n);
  };

  // ---------------- tier A: all-bf16 weights, atomic-free ------------------
  const size_t NEED_A = 232783872;  // ~222 MiB (proven to fit)
  if (ws_size >= NEED_A) {
    size_t off = 0;
    auto carve = [&](size_t bytes) -> char* {
      char* p = ws + off; off += (bytes + 255) & ~(size_t)255; return p;
    };
    u16* imgB  = (u16*)carve((size_t)B_ * DIN * 2);
    u16* txtB  = (u16*)carve((size_t)B_ * DIN * 2);
    u16* fc1B  = (u16*)carve((size_t)F * DIN * 2);   // dead after gated pass 2
    u16* fc2B  = (u16*)carve((size_t)F * DIN * 2);   // dead after gated pass 2
    u16* fc3B  = (u16*)carve((size_t)E * F * 2);
    u16* WqkvB = (u16*)carve((size_t)3 * E3 * E * 2);
    u16* WoB   = (u16*)carve((size_t)3 * E * E * 2);
    u16* W1B   = (u16*)carve((size_t)3 * E * E * 2);
    u16* W2B   = (u16*)carve((size_t)3 * E * E * 2);
    u16* WoutB = (u16*)carve((size_t)DIN * E * 2);
    char* U    = carve((size_t)B_ * F * 2);  // 64 MiB union region
    float* xF  = (float*)carve((size_t)B_ * E * 4);
    float* hF  = (float*)carve((size_t)B_ * E * 4);
    // fused phase: U holds fused[B, F] bf16, in-place gated
    u16* fusedB = (u16*)U;
    // post-fused overlay (fused dead after fc3)
    u16* kvB    = (u16*)(U);                   // [3*B, 2E] max 24 MiB
    u16* qB     = (u16*)(U + 25165824);        // [B, E] 4 MiB
    u16* ctxB   = (u16*)(U + 37748736);
    u16* attnB  = (u16*)(U + 37748736 + 16777216);
    u16* h1B    = (u16*)(U + 37748736 + 16777216 + 4194304);
    u16* xbB    = (u16*)(U + 37748736 + 16777216 + 8388608);
    // f32 partial scratch (8 MiB each) overlaying dead fc1B/fc2B
    float* PA = (float*)fc1B;
    float* PB = (float*)(fc1B + 4194304);
    float* PC = (float*)(fc1B + 8388608);
    float* PD = (float*)(fc1B + 12582912);
    float* PE = (float*)fc2B;
    float* PF = (float*)(fc2B + 4194304);

    cvt(image, imgB, (size_t)B_ * DIN);
    cvt(text,  txtB, (size_t)B_ * DIN);
    cvt(fc1_w, fc1B, (size_t)F * DIN);
    cvt(fc2_w, fc2B, (size_t)F * DIN);
    cvt(fc3_w, fc3B, (size_t)E * F);
    cvt(Wqkv,  WqkvB, (size_t)3 * E3 * E);
    cvt(Wo,    WoB,   (size_t)3 * E * E);
    cvt(W1,    W1B,   (size_t)3 * E * E);
    cvt(W2,    W2B,   (size_t)3 * E * E);
    cvt(WoutW, WoutB, (size_t)DIN * E);

    Ptr8 dumb{};
    // fused = txt@fc2^T + b2 (full F)
    gemm256<1><<<dim3(B_ / 256, F / 256), 512, 0, stream>>>(
        txtB, DIN, fc2B, DIN, fc2_b, nullptr, fusedB, dumb, F, DIN);
    // fused = (img@fc1^T + b1) * fused (in-place; fc1B/fc2B dead after)
    gemm256<4><<<dim3(B_ / 256, F / 256), 512, 0, stream>>>(
        imgB, DIN, fc1B, DIN, fc1_b, fusedB, fusedB, dumb, F, DIN);
    // fc3: 256-tile split-K=8 plain partials
    Ptr8 p8f{{xF, hF, PA, PB, PC, PD, PE, PF}};
    gemm256<0><<<dim3(B_ / 256, E / 256, 8), 512, 0, stream>>>(
        fusedB, F, fc3B, F, nullptr, nullptr, nullptr, p8f, E, F / 8);
    // x = LN(sum partials + fc3_b); ctx row 0
    resln_kernel<0><<<B_, 256, 0, stream>>>(
        p8f, 8, fc3_b, ln_g, ln_b, xF, ctxB, ctxOut, 0);

    Ptr8 p4{{hF, outF, PA, PB, nullptr, nullptr, nullptr, nullptr}};
    for (int i = 0; i < 3; ++i) {
      int L = i + 1;
      // KV for ctx rows 0..i: [L*B, 2E] with W rows E..3E of Wqkv[i]
      Ptr8 qkv1{{kvB, nullptr, nullptr, nullptr, nullptr, nullptr, nullptr, nullptr}};
      gemm_bt<1><<<dim3(L * B_ / 128, 2 * E / 128), TB, 0, stream>>>(
          ctxB, E, WqkvB + (size_t)i * E3 * E + (size_t)E * E, E,
          bqkv + (size_t)i * E3 + E, qkv1, 2 * E, E, E);
      // Q for newest row only
      Ptr8 qkv2{{qB, nullptr, nullptr, nullptr, nullptr, nullptr, nullptr, nullptr}};
      gemm_bt<1><<<dim3(B_ / 128, E / 128), TB, 0, stream>>>(
          ctxB + (size_t)i * B_ * E, E, WqkvB + (size_t)i * E3 * E, E,
          bqkv + (size_t)i * E3, qkv2, E, E, E);
      attn_kernel<<<B_ * 8, 64, 0, stream>>>(qB, E, kvB, 2 * E, E, attnB, L);
      // attn @ Wo^T: split-K=4 plain partials; bo folded into LN
      gemm_bt<0><<<dim3(B_ / 128, E / 128, 4), TB, 0, stream>>>(
          attnB, E, WoB + (size_t)i * E * E, E, nullptr, p4, E, E, E / 4);
      resln_kernel<1><<<B_, 256, 0, stream>>>(
          p4, 4, bo + (size_t)i * E, n1_g + (size_t)i * E, n1_b + (size_t)i * E,
          xF, xbB, nullptr, 0);
      // x @ W1^T: split-K=4; h1 = relu(sum + b1)
      gemm_bt<0><<<dim3(B_ / 128, E / 128, 4), TB, 0, stream>>>(
          xbB, E, W1B + (size_t)i * E * E, E, nullptr, p4, E, E, E / 4);
      relu_multi_kernel<<<B_ * E / 1024, 256, 0, stream>>>(
          p4, 4, b1 + (size_t)i * E, h1B);
      // h1 @ W2^T: split-K=4; b2 folded into LN
      gemm_bt<0><<<dim3(B_ / 128, E / 128, 4), TB, 0, stream>>>(
          h1B, E, W2B + (size_t)i * E * E, E, nullptr, p4, E, E, E / 4);
      resln_kernel<2><<<B_, 256, 0, stream>>>(
          p4, 4, b2 + (size_t)i * E, n2_g + (size_t)i * E, n2_b + (size_t)i * E,
          xF, ctxB + (size_t)(i + 1) * B_ * E, ctxOut, i + 1);
    }

    // final = x @ Wout^T: split-K=4 partials; combine + bout -> outF
    Ptr8 pfin{{hF, PA, PB, PC, nullptr, nullptr, nullptr, nullptr}};
    gemm_bt<0><<<dim3(B_ / 128, DIN / 128, 4), TB, 0, stream>>>(
        ctxB + (size_t)3 * B_ * E, E, WoutB, E, nullptr, pfin, DIN, E, E / 4);
    combine_out_kernel<<<B_ * DIN / 1024, 256, 0, stream>>>(pfin, 4, boutW, outF);
    return;
  }

  // ---------------- tier B: round-1 fallback (f32 weights, chunked) -------
  size_t off = 0;
  auto carve = [&](size_t bytes) -> char* {
    char* p = ws + off; off += (bytes + 255) & ~(size_t)255; return p;
  };
  u16* imgB   = (u16*)carve((size_t)B_ * DIN * 2);
  u16* txtB   = (u16*)carve((size_t)B_ * DIN * 2);
  u16* fusedC = (u16*)carve((size_t)B_ * CH * 2);
  u16* qkvB   = (u16*)carve((size_t)3 * B_ * E3 * 2);
  u16* ctxB   = (u16*)carve((size_t)4 * B_ * E * 2);
  u16* attnB  = (u16*)carve((size_t)B_ * E * 2);
  u16* h1B    = (u16*)carve((size_t)B_ * E * 2);
  u16* xbB    = (u16*)carve((size_t)B_ * E * 2);
  float* xF   = (float*)carve((size_t)B_ * E * 4);
  float* hF   = (float*)carve((size_t)B_ * E * 4);

  if (off > ws_size) {
    fill_kernel<<<(out_size + 255) / 256, 256, 0, stream>>>(outF, out_size, 12345.0f);
    return;
  }

  cvt(image, imgB, (size_t)B_ * DIN);
  cvt(text,  txtB, (size_t)B_ * DIN);
  hipMemsetAsync(hF, 0, (size_t)B_ * E * 4, stream);

  for (int c = 0; c < F / CH; ++c) {
    gemm_dual_wf32<<<dim3(B_ / 128, CH / 128), TB, 0, stream>>>(
        imgB, txtB, DIN,
        fc1_w + (size_t)c * CH * DIN, fc2_w + (size_t)c * CH * DIN, DIN,
        fc1_b + (size_t)c * CH, fc2_b + (size_t)c * CH, fusedC, CH, DIN);
    gemm_wf32<3><<<dim3(B_ / 128, E / 128, 2), TB, 0, stream>>>(
        fusedC, CH, fc3_w + (size_t)c * CH, F, nullptr, hF, E, CH, CH / 2);
  }
  {
    Ptr8 y1{{hF, nullptr, nullptr, nullptr, nullptr, nullptr, nullptr, nullptr}};
    resln_kernel<0><<<B_, 256, 0, stream>>>(y1, 1, fc3_b, ln_g, ln_b, xF, ctxB, ctxOut, 0);
  }

  for (int i = 0; i < 3; ++i) {
    int L = i + 1;
    gemm_wf32<1><<<dim3(L * B_ / 128, E3 / 128), TB, 0, stream>>>(
        ctxB, E, Wqkv + (size_t)i * E3 * E, E, bqkv + (size_t)i * E3, qkvB, E3, E, E);
    attn_kernel<<<B_ * 8, 64, 0, stream>>>(
        qkvB + (size_t)(L - 1) * B_ * E3, E3, qkvB + 1024, E3, 1024, attnB, L);
    gemm_wf32<0><<<dim3(B_ / 128, E / 128), TB, 0, stream>>>(
        attnB, E, Wo + (size_t)i * E * E, E, bo + (size_t)i * E, hF, E, E, E);
    Ptr8 y1{{hF, nullptr, nullptr, nullptr, nullptr, nullptr, nullptr, nullptr}};
    resln_kernel<1><<<B_, 256, 0, stream>>>(
        y1, 1, nullptr, n1_g + (size_t)i * E, n1_b + (size_t)i * E, xF, xbB, nullptr, 0);
    gemm_wf32<2><<<dim3(B_ / 128, E / 128), TB, 0, stream>>>(
        xbB, E, W1 + (size_t)i * E * E, E, b1 + (size_t)i * E, h1B, E, E, E);
    gemm_wf32<0><<<dim3(B_ / 128, E / 128), TB, 0, stream>>>(
        h1B, E, W2 + (size_t)i * E * E, E, b2 + (size_t)i * E, hF, E, E, E);
    resln_kernel<2><<<B_, 256, 0, stream>>>(
        y1, 1, nullptr, n2_g + (size_t)i * E, n2_b + (size_t)i * E, xF,
        ctxB + (size_t)(i + 1) * B_ * E, ctxOut, i + 1);
  }
  gemm_wf32<0><<<dim3(B_ / 128, DIN / 128), TB, 0, stream>>>(
      ctxB + (size_t)3 * B_ * E, E, WoutW, E, boutW, outF, DIN, E, E);
}